// Round 6
// baseline (268.195 us; speedup 1.0000x reference)
//
#include <hip/hip_runtime.h>

// Problem constants (fixed by setup_inputs)
constexpr int NB   = 4;
constexpr int SLEN = 5440;           // 64*64 + 32*32 + 16*16 + 8*8
constexpr long NTOK = (long)NB * SLEN; // 21760
constexpr int DD   = 256;
constexpr int NH   = 8;
constexpr int DHD  = 32;
constexpr int NL   = 4;
constexpr int NP   = 4;
constexpr int DFF  = 1024;

typedef __attribute__((ext_vector_type(8))) short short8;   // 8 x bf16
typedef __attribute__((ext_vector_type(4))) float f32x4;
typedef __attribute__((ext_vector_type(4))) unsigned short ushort4v;

static __device__ __forceinline__ unsigned short f2bf(float x) {
  union { float f; unsigned int u; } v; v.f = x;
  unsigned int r = v.u + 0x7fffu + ((v.u >> 16) & 1u);   // RNE
  return (unsigned short)(r >> 16);
}
static __device__ __forceinline__ float bf2f(unsigned short u) {
  union { unsigned int i; float f; } v; v.i = ((unsigned int)u) << 16; return v.f;
}
static __device__ __forceinline__ unsigned int pack2bf(float lo, float hi) {
  return (unsigned int)f2bf(lo) | ((unsigned int)f2bf(hi) << 16);
}

// B-fragment position for mfma_f32_16x16x32_bf16, weight K x N row-major.
// tile (kt,nt): lane l holds B[kt*32 + (l>>4)*8 + i][nt*16 + (l&15)], i=0..7
// NOTE: identical lane map serves as the A-fragment of the TRANSPOSED weight
// (A[m=l&15][k=lgrp*8+i]) -> W*f buffers are dual-use (swapped-operand MFMA).
static __device__ __forceinline__ long fragpos(int k, int n, int KT) {
  const int kt = k >> 5, i = k & 7;
  const int lane = ((k >> 3) & 3) * 16 + (n & 15);
  const int nt = n >> 4;
  return (((long)(nt * KT + kt) * 64 + lane) * 8 + i);
}

// ---------------------------------------------------------------------------
// K_prep_all: fragment W1, W2, Wv, [Woff|Wattn], Wo into bf16 MFMA layout.
// ---------------------------------------------------------------------------
__global__ __launch_bounds__(256) void k_prep_all(const float* __restrict__ W1,
                                                  const float* __restrict__ W2,
                                                  const float* __restrict__ Wv,
                                                  const float* __restrict__ Woff,
                                                  const float* __restrict__ Wattn,
                                                  const float* __restrict__ Wo,
                                                  unsigned short* __restrict__ W1f,
                                                  unsigned short* __restrict__ W2f,
                                                  unsigned short* __restrict__ Wvf,
                                                  unsigned short* __restrict__ Wqf,
                                                  unsigned short* __restrict__ Wof) {
  const int g = blockIdx.x * 256 + threadIdx.x;
  if (g < 262144) {                       // W1: 256 x 1024, KT=8
    const int k = g >> 10, n = g & 1023;
    W1f[fragpos(k, n, 8)] = f2bf(W1[g]);
  } else if (g < 524288) {                // W2: 1024 x 256, KT=32
    const int g2 = g - 262144;
    const int k = g2 >> 8, n = g2 & 255;
    W2f[fragpos(k, n, 32)] = f2bf(W2[g2]);
  } else if (g < 589824) {                // Wv: 256 x 256, KT=8
    const int g2 = g - 524288;
    const int k = g2 >> 8, n = g2 & 255;
    Wvf[fragpos(k, n, 8)] = f2bf(Wv[g2]);
  } else if (g < 688128) {                // Wq fused: 256 x 384 (=256 off + 128 attn)
    const int g2 = g - 589824;
    const int k = g2 / 384, n = g2 % 384;
    const float w = (n < 256) ? Woff[k * 256 + n] : Wattn[k * 128 + (n - 256)];
    Wqf[fragpos(k, n, 8)] = f2bf(w);
  } else if (g < 753664) {                // Wo: 256 x 256
    const int g2 = g - 688128;
    const int k = g2 >> 8, n = g2 & 255;
    Wof[fragpos(k, n, 8)] = f2bf(Wo[g2]);
  }
}

// ---------------------------------------------------------------------------
// K1: value(bf16) = src @ W_value + b_value. (unchanged, proven)
// ---------------------------------------------------------------------------
__global__ __launch_bounds__(256) void k_value_mfma(const float* __restrict__ src,
                                                    const unsigned short* __restrict__ Wvf,
                                                    const float* __restrict__ bv,
                                                    unsigned short* __restrict__ valbf) {
  __shared__ unsigned short Xs[32 * 256];
  const int t = threadIdx.x;
  const int w = t >> 6, lane = t & 63;
  const int lr = lane & 15, lgrp = lane >> 4;
  const long row0 = (long)blockIdx.x * 32;
  {
    const int r = t >> 3;
    const int c0 = (t & 7) * 32;
    const float* srcp = &src[(row0 + r) * DD + c0];
#pragma unroll
    for (int j = 0; j < 4; ++j) {
      const float4 a = *reinterpret_cast<const float4*>(&srcp[j * 8 + 0]);
      const float4 b = *reinterpret_cast<const float4*>(&srcp[j * 8 + 4]);
      short8 pk;
      pk[0] = (short)f2bf(a.x); pk[1] = (short)f2bf(a.y);
      pk[2] = (short)f2bf(a.z); pk[3] = (short)f2bf(a.w);
      pk[4] = (short)f2bf(b.x); pk[5] = (short)f2bf(b.y);
      pk[6] = (short)f2bf(b.z); pk[7] = (short)f2bf(b.w);
      int byte = r * 512 + (c0 + j * 8) * 2;
      byte ^= (r & 7) << 4;
      *reinterpret_cast<short8*>(reinterpret_cast<char*>(Xs) + byte) = pk;
    }
  }
  __syncthreads();
  short8 af[2][8];
#pragma unroll
  for (int mt = 0; mt < 2; ++mt)
#pragma unroll
    for (int kt = 0; kt < 8; ++kt) {
      const int row = mt * 16 + lr;
      int byte = row * 512 + kt * 64 + lgrp * 16;
      byte ^= (row & 7) << 4;
      af[mt][kt] = *reinterpret_cast<const short8*>(reinterpret_cast<const char*>(Xs) + byte);
    }
  f32x4 acc[2][4];
#pragma unroll
  for (int mt = 0; mt < 2; ++mt)
#pragma unroll
    for (int n = 0; n < 4; ++n) acc[mt][n] = (f32x4){0.f, 0.f, 0.f, 0.f};
#pragma unroll
  for (int n = 0; n < 4; ++n) {
    const int nt = w * 4 + n;
#pragma unroll
    for (int kt = 0; kt < 8; ++kt) {
      const short8 bf_ = *reinterpret_cast<const short8*>(&Wvf[((nt * 8 + kt) * 64 + lane) * 8]);
#pragma unroll
      for (int mt = 0; mt < 2; ++mt)
        acc[mt][n] = __builtin_amdgcn_mfma_f32_16x16x32_bf16(af[mt][kt], bf_, acc[mt][n], 0, 0, 0);
    }
  }
#pragma unroll
  for (int n = 0; n < 4; ++n) {
    const int col = w * 64 + n * 16 + lr;
    const float bb = bv[col];
#pragma unroll
    for (int mt = 0; mt < 2; ++mt)
#pragma unroll
      for (int j = 0; j < 4; ++j) {
        const int row = mt * 16 + lgrp * 4 + j;
        valbf[(row0 + row) * DD + col] = f2bf(acc[mt][n][j] + bb);
      }
  }
}

// ---------------------------------------------------------------------------
// K2: q = src+pos; off(bf16) = q@W_off+b_off; attn(bf16) = softmax16(...).
// ---------------------------------------------------------------------------
__global__ __launch_bounds__(256) void k_qproj_mfma(const float* __restrict__ src,
                                                    const float* __restrict__ pos,
                                                    const unsigned short* __restrict__ Wqf,
                                                    const float* __restrict__ boff,
                                                    const float* __restrict__ battn,
                                                    unsigned short* __restrict__ offbf,
                                                    unsigned short* __restrict__ attnbf) {
  __shared__ unsigned short Xs[32 * 256];
  const int t = threadIdx.x;
  const int w = t >> 6, lane = t & 63;
  const int lr = lane & 15, lgrp = lane >> 4;
  const long row0 = (long)blockIdx.x * 32;
  {
    const int r = t >> 3;
    const int c0 = (t & 7) * 32;
    const float* sp = &src[(row0 + r) * DD + c0];
    const float* pp = &pos[(row0 + r) * DD + c0];
#pragma unroll
    for (int j = 0; j < 4; ++j) {
      const float4 a = *reinterpret_cast<const float4*>(&sp[j * 8 + 0]);
      const float4 b = *reinterpret_cast<const float4*>(&sp[j * 8 + 4]);
      const float4 c = *reinterpret_cast<const float4*>(&pp[j * 8 + 0]);
      const float4 d = *reinterpret_cast<const float4*>(&pp[j * 8 + 4]);
      short8 pk;
      pk[0] = (short)f2bf(a.x + c.x); pk[1] = (short)f2bf(a.y + c.y);
      pk[2] = (short)f2bf(a.z + c.z); pk[3] = (short)f2bf(a.w + c.w);
      pk[4] = (short)f2bf(b.x + d.x); pk[5] = (short)f2bf(b.y + d.y);
      pk[6] = (short)f2bf(b.z + d.z); pk[7] = (short)f2bf(b.w + d.w);
      int byte = r * 512 + (c0 + j * 8) * 2;
      byte ^= (r & 7) << 4;
      *reinterpret_cast<short8*>(reinterpret_cast<char*>(Xs) + byte) = pk;
    }
  }
  __syncthreads();
  short8 af[2][8];
#pragma unroll
  for (int mt = 0; mt < 2; ++mt)
#pragma unroll
    for (int kt = 0; kt < 8; ++kt) {
      const int row = mt * 16 + lr;
      int byte = row * 512 + kt * 64 + lgrp * 16;
      byte ^= (row & 7) << 4;
      af[mt][kt] = *reinterpret_cast<const short8*>(reinterpret_cast<const char*>(Xs) + byte);
    }
  f32x4 acc[2][6];
#pragma unroll
  for (int mt = 0; mt < 2; ++mt)
#pragma unroll
    for (int i = 0; i < 6; ++i) acc[mt][i] = (f32x4){0.f, 0.f, 0.f, 0.f};
#pragma unroll
  for (int i = 0; i < 6; ++i) {
    const int ntg = w * 6 + i;
#pragma unroll
    for (int kt = 0; kt < 8; ++kt) {
      const short8 bf_ = *reinterpret_cast<const short8*>(&Wqf[((ntg * 8 + kt) * 64 + lane) * 8]);
#pragma unroll
      for (int mt = 0; mt < 2; ++mt)
        acc[mt][i] = __builtin_amdgcn_mfma_f32_16x16x32_bf16(af[mt][kt], bf_, acc[mt][i], 0, 0, 0);
    }
  }
#pragma unroll
  for (int i = 0; i < 6; ++i) {
    const int ntg = w * 6 + i;
    if (ntg < 16) {
      const int col = ntg * 16 + lr;
      const float bb = boff[col];
#pragma unroll
      for (int mt = 0; mt < 2; ++mt)
#pragma unroll
        for (int j = 0; j < 4; ++j) {
          const int row = mt * 16 + lgrp * 4 + j;
          offbf[(row0 + row) * 256 + col] = f2bf(acc[mt][i][j] + bb);
        }
    } else {
      const int na = ntg - 16;       // head index
      const float bb = battn[na * 16 + lr];
#pragma unroll
      for (int mt = 0; mt < 2; ++mt)
#pragma unroll
        for (int j = 0; j < 4; ++j) {
          const int row = mt * 16 + lgrp * 4 + j;
          const float v = acc[mt][i][j] + bb;
          float m = v;
#pragma unroll
          for (int d_ = 1; d_ <= 8; d_ <<= 1) m = fmaxf(m, __shfl_xor(m, d_, 16));
          const float e = __expf(v - m);
          float s = e;
#pragma unroll
          for (int d_ = 1; d_ <= 8; d_ <<= 1) s += __shfl_xor(s, d_, 16);
          attnbf[(row0 + row) * 128 + na * 16 + lr] = f2bf(e / s);
        }
    }
  }
}

// ---------------------------------------------------------------------------
// K3: deformable sampling v4. XCD-image swizzle: blocks of image b map to
// XCD pair {2b,2b+1} (per-XCD L2 slice = 2.8MB value < 4MB). SoA LDS:
// writes lane-linear (0 conflicts), reads broadcast/2-way (free).
// ---------------------------------------------------------------------------
__global__ __launch_bounds__(256) void k_sample3(const unsigned short* __restrict__ valbf,
                                                 const unsigned short* __restrict__ offbf,
                                                 const unsigned short* __restrict__ attnbf,
                                                 const float* __restrict__ refp,
                                                 unsigned short* __restrict__ src2bf) {
  __shared__ int   sIdx[4][2][4][64];
  __shared__ float sW  [4][2][4][64];
  const int t = threadIdx.x;
  const int w = t >> 6, lane = t & 63;
  const int hg = lane >> 3, li = lane & 7;
  // XCD swizzle: hw block B -> (image, intra-image index)
  const int B = blockIdx.x;
  const int bimg = (B & 7) >> 1;
  const int ii = ((B >> 3) << 1) + (B & 1);     // 0..1359
  const long n = (long)bimg * SLEN + ii * 4 + w;
  const long bOff = (long)bimg * SLEN;

  const int   WlA[4] = {64, 32, 16, 8};
  const float rWA[4] = {1.f / 64.f, 1.f / 32.f, 1.f / 16.f, 1.f / 8.f};
  const int   stA[4] = {0, 4096, 5120, 5376};

#pragma unroll
  for (int q = 0; q < 2; ++q) {
    const int pt = 2 * li + q;
    const int l = pt >> 2, p = pt & 3;
    const int Wi = WlA[l];
    const float Wf = (float)Wi, rW = rWA[l];
    const float rx = refp[(n * 4 + l) * 2 + 0];
    const float ry = refp[(n * 4 + l) * 2 + 1];
    const float aw = bf2f(attnbf[n * 128 + hg * 16 + pt]);
    const int oi = ((hg * 4 + l) * 4 + p) * 2;
    const unsigned int opk = *reinterpret_cast<const unsigned int*>(&offbf[n * 256 + oi]);
    const float ox = bf2f((unsigned short)(opk & 0xffff));
    const float oy = bf2f((unsigned short)(opk >> 16));
    const float px = (rx + ox * rW) * Wf - 0.5f;
    const float py = (ry + oy * rW) * Wf - 0.5f;
    const float x0f = floorf(px), y0f = floorf(py);
    const float fx = px - x0f, fy = py - y0f;
    const int x0 = (int)x0f, y0 = (int)y0f;
#pragma unroll
    for (int c = 0; c < 4; ++c) {
      const int dx = c & 1, dy = c >> 1;
      const int xi = x0 + dx, yi = y0 + dy;
      const float cw = (dx ? fx : 1.f - fx) * (dy ? fy : 1.f - fy);
      const bool valid = (xi >= 0) && (xi < Wi) && (yi >= 0) && (yi < Wi);
      const int xc = min(max(xi, 0), Wi - 1);
      const int yc = min(max(yi, 0), Wi - 1);
      const long flat = stA[l] + yc * Wi + xc;
      sIdx[w][q][c][lane] = (int)((bOff + flat) * DD + hg * DHD);
      sW[w][q][c][lane]   = aw * cw * (valid ? 1.f : 0.f);
    }
  }
  __syncthreads();

  float4 acc = make_float4(0.f, 0.f, 0.f, 0.f);
#pragma unroll 4
  for (int pt = 0; pt < 16; ++pt) {
    const int q = pt & 1;
    const int ls = hg * 8 + (pt >> 1);
    const int   i0 = sIdx[w][q][0][ls], i1 = sIdx[w][q][1][ls];
    const int   i2 = sIdx[w][q][2][ls], i3 = sIdx[w][q][3][ls];
    const float w0 = sW[w][q][0][ls], w1 = sW[w][q][1][ls];
    const float w2 = sW[w][q][2][ls], w3 = sW[w][q][3][ls];
    const ushort4v u0 = *reinterpret_cast<const ushort4v*>(&valbf[(long)i0 + li * 4]);
    const ushort4v u1 = *reinterpret_cast<const ushort4v*>(&valbf[(long)i1 + li * 4]);
    const ushort4v u2 = *reinterpret_cast<const ushort4v*>(&valbf[(long)i2 + li * 4]);
    const ushort4v u3 = *reinterpret_cast<const ushort4v*>(&valbf[(long)i3 + li * 4]);
    acc.x += w0 * bf2f(u0[0]) + w1 * bf2f(u1[0]) + w2 * bf2f(u2[0]) + w3 * bf2f(u3[0]);
    acc.y += w0 * bf2f(u0[1]) + w1 * bf2f(u1[1]) + w2 * bf2f(u2[1]) + w3 * bf2f(u3[1]);
    acc.z += w0 * bf2f(u0[2]) + w1 * bf2f(u1[2]) + w2 * bf2f(u2[2]) + w3 * bf2f(u3[2]);
    acc.w += w0 * bf2f(u0[3]) + w1 * bf2f(u1[3]) + w2 * bf2f(u2[3]) + w3 * bf2f(u3[3]);
  }
  ushort4v o;
  o[0] = f2bf(acc.x); o[1] = f2bf(acc.y); o[2] = f2bf(acc.z); o[3] = f2bf(acc.w);
  *reinterpret_cast<ushort4v*>(&src2bf[n * DD + hg * DHD + li * 4]) = o;
}

// ---------------------------------------------------------------------------
// K4: xbf = bf16(LN1(src + src2bf @ W_out + b_out)). (unchanged, proven)
// ---------------------------------------------------------------------------
__global__ __launch_bounds__(256) void k_outproj_mfma(const unsigned short* __restrict__ src2bf,
                                                      const unsigned short* __restrict__ Wof,
                                                      const float* __restrict__ bo,
                                                      const float* __restrict__ src,
                                                      const float* __restrict__ g1,
                                                      const float* __restrict__ b1g,
                                                      unsigned short* __restrict__ xbf) {
  __shared__ float rsum[32][4];
  __shared__ float rssq[32][4];
  const int t = threadIdx.x;
  const int w = t >> 6, lane = t & 63;
  const int lr = lane & 15, lgrp = lane >> 4;
  const long row0 = (long)blockIdx.x * 32;

  short8 af[2][8];
#pragma unroll
  for (int mt = 0; mt < 2; ++mt)
#pragma unroll
    for (int kt = 0; kt < 8; ++kt)
      af[mt][kt] = *reinterpret_cast<const short8*>(
          &src2bf[(row0 + mt * 16 + lr) * DD + kt * 32 + lgrp * 8]);

  f32x4 acc[2][4];
#pragma unroll
  for (int mt = 0; mt < 2; ++mt)
#pragma unroll
    for (int n = 0; n < 4; ++n) acc[mt][n] = (f32x4){0.f, 0.f, 0.f, 0.f};
#pragma unroll
  for (int n = 0; n < 4; ++n) {
    const int nt = w * 4 + n;
#pragma unroll
    for (int kt = 0; kt < 8; ++kt) {
      const short8 bf_ = *reinterpret_cast<const short8*>(&Wof[((nt * 8 + kt) * 64 + lane) * 8]);
#pragma unroll
      for (int mt = 0; mt < 2; ++mt)
        acc[mt][n] = __builtin_amdgcn_mfma_f32_16x16x32_bf16(af[mt][kt], bf_, acc[mt][n], 0, 0, 0);
    }
  }
  float bc[4], gc[4], bgc[4];
#pragma unroll
  for (int n = 0; n < 4; ++n) {
    const int col = w * 64 + n * 16 + lr;
    bc[n] = bo[col]; gc[n] = g1[col]; bgc[n] = b1g[col];
  }
  float vals[2][4][4];
#pragma unroll
  for (int mt = 0; mt < 2; ++mt)
#pragma unroll
    for (int j = 0; j < 4; ++j) {
      const int row = mt * 16 + lgrp * 4 + j;
      float s = 0.f, ss = 0.f;
#pragma unroll
      for (int n = 0; n < 4; ++n) {
        const int col = w * 64 + n * 16 + lr;
        const float v = acc[mt][n][j] + bc[n] + src[(row0 + row) * DD + col];
        vals[mt][n][j] = v;
        s += v; ss += v * v;
      }
#pragma unroll
      for (int m = 1; m <= 8; m <<= 1) { s += __shfl_xor(s, m, 64); ss += __shfl_xor(ss, m, 64); }
      if (lr == 0) { rsum[row][w] = s; rssq[row][w] = ss; }
    }
  __syncthreads();
#pragma unroll
  for (int mt = 0; mt < 2; ++mt)
#pragma unroll
    for (int j = 0; j < 4; ++j) {
      const int row = mt * 16 + lgrp * 4 + j;
      const float s  = rsum[row][0] + rsum[row][1] + rsum[row][2] + rsum[row][3];
      const float ss = rssq[row][0] + rssq[row][1] + rssq[row][2] + rssq[row][3];
      const float mean = s * (1.f / 256.f);
      const float inv  = rsqrtf(ss * (1.f / 256.f) - mean * mean + 1e-5f);
#pragma unroll
      for (int n = 0; n < 4; ++n) {
        const int col = w * 64 + n * 16 + lr;
        xbf[(row0 + row) * DD + col] = f2bf((vals[mt][n][j] - mean) * inv * gc[n] + bgc[n]);
      }
    }
}

// ---------------------------------------------------------------------------
// K5: FUSED FFN via swapped-operand MFMA. out = LN2(x + relu(x@W1+b1)@W2 + b2)
// Per 64-row block (4 waves, N-split): compute H^T = relu(W1^T · X^T) in
// 256-hdim chunks (A = W1f frag, B = X row-major frag — existing layouts are
// exactly the transposed-operand fragments), stage H^T chunk in LDS (32KB,
// swizzled), then out^T += W2^T · H^T (A = W2f frag, B = H from LDS).
// No H in HBM (saves 89MB round-trip). Fused bias/ReLU/residual/LN2.
// ---------------------------------------------------------------------------
__global__ __launch_bounds__(256) void k_ffn_fused(const unsigned short* __restrict__ xbf,
                                                   const unsigned short* __restrict__ W1f,
                                                   const float* __restrict__ b1v,
                                                   const unsigned short* __restrict__ W2f,
                                                   const float* __restrict__ b2v_,
                                                   const float* __restrict__ g2,
                                                   const float* __restrict__ b2g,
                                                   float* __restrict__ outp) {
  __shared__ unsigned short Xs[64 * 256];   // 32 KB, swizzled [xr][feat]
  __shared__ unsigned short Hc[64 * 256];   // 32 KB, swizzled [xr][hdim-local]
  __shared__ float rsum[64][4];
  __shared__ float rssq[64][4];
  const int t = threadIdx.x;
  const int w = t >> 6, lane = t & 63;
  const int lr = lane & 15, lgrp = lane >> 4;
  const long row0 = (long)blockIdx.x * 64;

  // stage X -> Xs (bf16 copy, swizzled)
  {
    const int r = t >> 2;
    const int c0 = (t & 3) * 64;
    const unsigned short* sp = &xbf[(row0 + r) * DD + c0];
#pragma unroll
    for (int j = 0; j < 8; ++j) {
      int byte = r * 512 + (c0 + j * 8) * 2;
      byte ^= (r & 7) << 4;
      *reinterpret_cast<short8*>(reinterpret_cast<char*>(Xs) + byte) =
          *reinterpret_cast<const short8*>(&sp[j * 8]);
    }
  }
  __syncthreads();

  f32x4 ff[4][4];   // [oc][n] : out^T accumulators (K-accumulated over chunks)
#pragma unroll
  for (int oc = 0; oc < 4; ++oc)
#pragma unroll
    for (int n = 0; n < 4; ++n) ff[oc][n] = (f32x4){0.f, 0.f, 0.f, 0.f};

  for (int c = 0; c < 4; ++c) {
    // ---- phase 1: H^T chunk (wave w: hdims c*256 + w*64 .. +64) ----
    f32x4 acc[4][4];  // [m=hdim-tile][n=xr-tile]
#pragma unroll
    for (int m = 0; m < 4; ++m)
#pragma unroll
      for (int n = 0; n < 4; ++n) acc[m][n] = (f32x4){0.f, 0.f, 0.f, 0.f};
#pragma unroll
    for (int kt = 0; kt < 8; ++kt) {
      short8 bx[4];
#pragma unroll
      for (int n = 0; n < 4; ++n) {
        const int row = n * 16 + lr;
        int byte = row * 512 + kt * 64 + lgrp * 16;
        byte ^= (row & 7) << 4;
        bx[n] = *reinterpret_cast<const short8*>(reinterpret_cast<const char*>(Xs) + byte);
      }
#pragma unroll
      for (int m = 0; m < 4; ++m) {
        const int ntg = c * 16 + w * 4 + m;     // hdim tile in W1f
        const short8 aw1 = *reinterpret_cast<const short8*>(&W1f[((ntg * 8 + kt) * 64 + lane) * 8]);
#pragma unroll
        for (int n = 0; n < 4; ++n)
          acc[m][n] = __builtin_amdgcn_mfma_f32_16x16x32_bf16(aw1, bx[n], acc[m][n], 0, 0, 0);
      }
    }
    __syncthreads();   // previous chunk's Hc fully consumed
    // bias + relu -> Hc (lane holds 4 consecutive hdims per (m,n): pack 2x bf16)
#pragma unroll
    for (int m = 0; m < 4; ++m) {
      const int hl = w * 64 + m * 16 + lgrp * 4;       // hdim local to chunk
      const float4 b1q = *reinterpret_cast<const float4*>(&b1v[c * 256 + hl]);
#pragma unroll
      for (int n = 0; n < 4; ++n) {
        const int xr = n * 16 + lr;
        int2 pk;
        pk.x = (int)pack2bf(fmaxf(acc[m][n][0] + b1q.x, 0.f),
                            fmaxf(acc[m][n][1] + b1q.y, 0.f));
        pk.y = (int)pack2bf(fmaxf(acc[m][n][2] + b1q.z, 0.f),
                            fmaxf(acc[m][n][3] + b1q.w, 0.f));
        int byte = xr * 512 + hl * 2;
        byte ^= (xr & 7) << 4;
        *reinterpret_cast<int2*>(reinterpret_cast<char*>(Hc) + byte) = pk;
      }
    }
    __syncthreads();   // Hc chunk ready
    // ---- phase 2: out^T += W2^T[c-chunk] · H^T ----
#pragma unroll
    for (int ktl = 0; ktl < 8; ++ktl) {
      short8 bh[4];
#pragma unroll
      for (int n = 0; n < 4; ++n) {
        const int xr = n * 16 + lr;
        int byte = xr * 512 + ktl * 64 + lgrp * 16;
        byte ^= (xr & 7) << 4;
        bh[n] = *reinterpret_cast<const short8*>(reinterpret_cast<const char*>(Hc) + byte);
      }
#pragma unroll
      for (int oc = 0; oc < 4; ++oc) {
        const int nt = w * 4 + oc;
        const int ktg = c * 8 + ktl;
        const short8 aw2 = *reinterpret_cast<const short8*>(&W2f[((nt * 32 + ktg) * 64 + lane) * 8]);
#pragma unroll
        for (int n = 0; n < 4; ++n)
          ff[oc][n] = __builtin_amdgcn_mfma_f32_16x16x32_bf16(aw2, bh[n], ff[oc][n], 0, 0, 0);
      }
    }
  }

  // ---- epilogue: v = ff + b2 + x (residual), LN2 over 256 cols, store ----
  float4 b2q[4], g2q[4], bgq[4];
#pragma unroll
  for (int oc = 0; oc < 4; ++oc) {
    const int colb = w * 64 + oc * 16 + lgrp * 4;
    b2q[oc] = *reinterpret_cast<const float4*>(&b2v_[colb]);
    g2q[oc] = *reinterpret_cast<const float4*>(&g2[colb]);
    bgq[oc] = *reinterpret_cast<const float4*>(&b2g[colb]);
  }
  float vals[4][4][4];   // [oc][n][j]
#pragma unroll
  for (int n = 0; n < 4; ++n) {
    const long token = row0 + n * 16 + lr;
    float s = 0.f, ss = 0.f;
#pragma unroll
    for (int oc = 0; oc < 4; ++oc) {
      const int colb = w * 64 + oc * 16 + lgrp * 4;
      const ushort4v rv = *reinterpret_cast<const ushort4v*>(&xbf[token * DD + colb]);
#pragma unroll
      for (int j = 0; j < 4; ++j) {
        const float v = ff[oc][n][j] + b2q[oc][j] + bf2f(rv[j]);
        vals[oc][n][j] = v;
        s += v; ss += v * v;
      }
    }
    // reduce across lgrp (lanes lr+16*lgrp hold disjoint col ranges of token)
    s += __shfl_xor(s, 16, 64); s += __shfl_xor(s, 32, 64);
    ss += __shfl_xor(ss, 16, 64); ss += __shfl_xor(ss, 32, 64);
    if (lgrp == 0) { rsum[n * 16 + lr][w] = s; rssq[n * 16 + lr][w] = ss; }
  }
  __syncthreads();
#pragma unroll
  for (int n = 0; n < 4; ++n) {
    const int tl = n * 16 + lr;
    const float s  = rsum[tl][0] + rsum[tl][1] + rsum[tl][2] + rsum[tl][3];
    const float ss = rssq[tl][0] + rssq[tl][1] + rssq[tl][2] + rssq[tl][3];
    const float mean = s * (1.f / 256.f);
    const float inv  = rsqrtf(ss * (1.f / 256.f) - mean * mean + 1e-5f);
#pragma unroll
    for (int oc = 0; oc < 4; ++oc) {
      float4 o;
      o.x = (vals[oc][n][0] - mean) * inv * g2q[oc].x + bgq[oc].x;
      o.y = (vals[oc][n][1] - mean) * inv * g2q[oc].y + bgq[oc].y;
      o.z = (vals[oc][n][2] - mean) * inv * g2q[oc].z + bgq[oc].z;
      o.w = (vals[oc][n][3] - mean) * inv * g2q[oc].w + bgq[oc].w;
      *reinterpret_cast<float4*>(&outp[(row0 + tl) * DD + w * 64 + oc * 16 + lgrp * 4]) = o;
    }
  }
}

extern "C" void kernel_launch(void* const* d_in, const int* in_sizes, int n_in,
                              void* d_out, int out_size, void* d_ws, size_t ws_size,
                              hipStream_t stream) {
  const float* src  = (const float*)d_in[0];
  const float* refp = (const float*)d_in[1];
  const float* pos  = (const float*)d_in[5];
  const float* Wv   = (const float*)d_in[6];
  const float* bv   = (const float*)d_in[7];
  const float* Woff = (const float*)d_in[8];
  const float* boff = (const float*)d_in[9];
  const float* Wat  = (const float*)d_in[10];
  const float* bat  = (const float*)d_in[11];
  const float* Wo   = (const float*)d_in[12];
  const float* bo   = (const float*)d_in[13];
  const float* g1   = (const float*)d_in[14];
  const float* b1g  = (const float*)d_in[15];
  const float* W1   = (const float*)d_in[16];
  const float* b1f  = (const float*)d_in[17];
  const float* W2   = (const float*)d_in[18];
  const float* b2f  = (const float*)d_in[19];
  const float* g2   = (const float*)d_in[20];
  const float* b2g  = (const float*)d_in[21];
  float* out = (float*)d_out;

  // workspace (~51.7 MB, all bf16 intermediates; no hfrag)
  unsigned short* valbf  = (unsigned short*)d_ws;       // NTOK*256
  unsigned short* offbf  = valbf + NTOK * 256;          // NTOK*256
  unsigned short* attnbf = offbf + NTOK * 256;          // NTOK*128
  unsigned short* src2bf = attnbf + NTOK * 128;         // NTOK*256
  unsigned short* xbf    = src2bf + NTOK * 256;         // NTOK*256
  unsigned short* W1f = xbf + NTOK * 256;               // 262144
  unsigned short* W2f = W1f + 262144;                   // 262144
  unsigned short* Wvf = W2f + 262144;                   // 65536
  unsigned short* Wqf = Wvf + 65536;                    // 98304
  unsigned short* Wof = Wqf + 98304;                    // 65536

  hipLaunchKernelGGL(k_prep_all, dim3(2944), dim3(256), 0, stream,
                     W1, W2, Wv, Woff, Wat, Wo, W1f, W2f, Wvf, Wqf, Wof);
  hipLaunchKernelGGL(k_value_mfma, dim3((int)(NTOK / 32)), dim3(256), 0, stream,
                     src, Wvf, bv, valbf);
  hipLaunchKernelGGL(k_qproj_mfma, dim3((int)(NTOK / 32)), dim3(256), 0, stream,
                     src, pos, Wqf, boff, bat, offbf, attnbf);
  hipLaunchKernelGGL(k_sample3, dim3((int)(NTOK / 4)), dim3(256), 0, stream,
                     valbf, offbf, attnbf, refp, src2bf);
  hipLaunchKernelGGL(k_outproj_mfma, dim3((int)(NTOK / 32)), dim3(256), 0, stream,
                     src2bf, Wof, bo, src, g1, b1g, xbf);
  hipLaunchKernelGGL(k_ffn_fused, dim3((int)(NTOK / 64)), dim3(256), 0, stream,
                     xbf, W1f, b1f, W2f, b2f, g2, b2g, out);
}

// Round 7
// 213.203 us; speedup vs baseline: 1.2579x; 1.2579x over previous
//
#include <hip/hip_runtime.h>

// Problem constants (fixed by setup_inputs)
constexpr int NB   = 4;
constexpr int SLEN = 5440;           // 64*64 + 32*32 + 16*16 + 8*8
constexpr long NTOK = (long)NB * SLEN; // 21760
constexpr int DD   = 256;
constexpr int NH   = 8;
constexpr int DHD  = 32;
constexpr int NL   = 4;
constexpr int NP   = 4;
constexpr int DFF  = 1024;

typedef __attribute__((ext_vector_type(8))) short short8;   // 8 x bf16
typedef __attribute__((ext_vector_type(4))) float f32x4;
typedef __attribute__((ext_vector_type(4))) unsigned short ushort4v;

static __device__ __forceinline__ unsigned short f2bf(float x) {
  union { float f; unsigned int u; } v; v.f = x;
  unsigned int r = v.u + 0x7fffu + ((v.u >> 16) & 1u);   // RNE
  return (unsigned short)(r >> 16);
}
static __device__ __forceinline__ float bf2f(unsigned short u) {
  union { unsigned int i; float f; } v; v.i = ((unsigned int)u) << 16; return v.f;
}
static __device__ __forceinline__ unsigned int pack2bf(float lo, float hi) {
  return (unsigned int)f2bf(lo) | ((unsigned int)f2bf(hi) << 16);
}

// B-fragment position for mfma_f32_16x16x32_bf16, weight K x N row-major.
// tile (kt,nt): lane l holds B[kt*32 + (l>>4)*8 + i][nt*16 + (l&15)], i=0..7
// Dual-use: same registers read as the A-fragment give A = W^T (swapped-op).
static __device__ __forceinline__ long fragpos(int k, int n, int KT) {
  const int kt = k >> 5, i = k & 7;
  const int lane = ((k >> 3) & 3) * 16 + (n & 15);
  const int nt = n >> 4;
  return (((long)(nt * KT + kt) * 64 + lane) * 8 + i);
}

// ---------------------------------------------------------------------------
// K_prep_all: fragment W1, W2, Wv, [Woff|Wattn], Wo into bf16 MFMA layout.
// ---------------------------------------------------------------------------
__global__ __launch_bounds__(256) void k_prep_all(const float* __restrict__ W1,
                                                  const float* __restrict__ W2,
                                                  const float* __restrict__ Wv,
                                                  const float* __restrict__ Woff,
                                                  const float* __restrict__ Wattn,
                                                  const float* __restrict__ Wo,
                                                  unsigned short* __restrict__ W1f,
                                                  unsigned short* __restrict__ W2f,
                                                  unsigned short* __restrict__ Wvf,
                                                  unsigned short* __restrict__ Wqf,
                                                  unsigned short* __restrict__ Wof) {
  const int g = blockIdx.x * 256 + threadIdx.x;
  if (g < 262144) {                       // W1: 256 x 1024, KT=8
    const int k = g >> 10, n = g & 1023;
    W1f[fragpos(k, n, 8)] = f2bf(W1[g]);
  } else if (g < 524288) {                // W2: 1024 x 256, KT=32
    const int g2 = g - 262144;
    const int k = g2 >> 8, n = g2 & 255;
    W2f[fragpos(k, n, 32)] = f2bf(W2[g2]);
  } else if (g < 589824) {                // Wv: 256 x 256, KT=8
    const int g2 = g - 524288;
    const int k = g2 >> 8, n = g2 & 255;
    Wvf[fragpos(k, n, 8)] = f2bf(Wv[g2]);
  } else if (g < 688128) {                // Wq fused: 256 x 384 (=256 off + 128 attn)
    const int g2 = g - 589824;
    const int k = g2 / 384, n = g2 % 384;
    const float w = (n < 256) ? Woff[k * 256 + n] : Wattn[k * 128 + (n - 256)];
    Wqf[fragpos(k, n, 8)] = f2bf(w);
  } else if (g < 753664) {                // Wo: 256 x 256
    const int g2 = g - 688128;
    const int k = g2 >> 8, n = g2 & 255;
    Wof[fragpos(k, n, 8)] = f2bf(Wo[g2]);
  }
}

// ---------------------------------------------------------------------------
// K1: value(bf16) = src @ W_value + b_value. (unchanged, proven)
// ---------------------------------------------------------------------------
__global__ __launch_bounds__(256) void k_value_mfma(const float* __restrict__ src,
                                                    const unsigned short* __restrict__ Wvf,
                                                    const float* __restrict__ bv,
                                                    unsigned short* __restrict__ valbf) {
  __shared__ unsigned short Xs[32 * 256];
  const int t = threadIdx.x;
  const int w = t >> 6, lane = t & 63;
  const int lr = lane & 15, lgrp = lane >> 4;
  const long row0 = (long)blockIdx.x * 32;
  {
    const int r = t >> 3;
    const int c0 = (t & 7) * 32;
    const float* srcp = &src[(row0 + r) * DD + c0];
#pragma unroll
    for (int j = 0; j < 4; ++j) {
      const float4 a = *reinterpret_cast<const float4*>(&srcp[j * 8 + 0]);
      const float4 b = *reinterpret_cast<const float4*>(&srcp[j * 8 + 4]);
      short8 pk;
      pk[0] = (short)f2bf(a.x); pk[1] = (short)f2bf(a.y);
      pk[2] = (short)f2bf(a.z); pk[3] = (short)f2bf(a.w);
      pk[4] = (short)f2bf(b.x); pk[5] = (short)f2bf(b.y);
      pk[6] = (short)f2bf(b.z); pk[7] = (short)f2bf(b.w);
      int byte = r * 512 + (c0 + j * 8) * 2;
      byte ^= (r & 7) << 4;
      *reinterpret_cast<short8*>(reinterpret_cast<char*>(Xs) + byte) = pk;
    }
  }
  __syncthreads();
  short8 af[2][8];
#pragma unroll
  for (int mt = 0; mt < 2; ++mt)
#pragma unroll
    for (int kt = 0; kt < 8; ++kt) {
      const int row = mt * 16 + lr;
      int byte = row * 512 + kt * 64 + lgrp * 16;
      byte ^= (row & 7) << 4;
      af[mt][kt] = *reinterpret_cast<const short8*>(reinterpret_cast<const char*>(Xs) + byte);
    }
  f32x4 acc[2][4];
#pragma unroll
  for (int mt = 0; mt < 2; ++mt)
#pragma unroll
    for (int n = 0; n < 4; ++n) acc[mt][n] = (f32x4){0.f, 0.f, 0.f, 0.f};
#pragma unroll
  for (int n = 0; n < 4; ++n) {
    const int nt = w * 4 + n;
#pragma unroll
    for (int kt = 0; kt < 8; ++kt) {
      const short8 bf_ = *reinterpret_cast<const short8*>(&Wvf[((nt * 8 + kt) * 64 + lane) * 8]);
#pragma unroll
      for (int mt = 0; mt < 2; ++mt)
        acc[mt][n] = __builtin_amdgcn_mfma_f32_16x16x32_bf16(af[mt][kt], bf_, acc[mt][n], 0, 0, 0);
    }
  }
#pragma unroll
  for (int n = 0; n < 4; ++n) {
    const int col = w * 64 + n * 16 + lr;
    const float bb = bv[col];
#pragma unroll
    for (int mt = 0; mt < 2; ++mt)
#pragma unroll
      for (int j = 0; j < 4; ++j) {
        const int row = mt * 16 + lgrp * 4 + j;
        valbf[(row0 + row) * DD + col] = f2bf(acc[mt][n][j] + bb);
      }
  }
}

// ---------------------------------------------------------------------------
// K2: q = src+pos; off(bf16) = q@W_off+b_off; attn(f32) = softmax16(...).
// ---------------------------------------------------------------------------
__global__ __launch_bounds__(256) void k_qproj_mfma(const float* __restrict__ src,
                                                    const float* __restrict__ pos,
                                                    const unsigned short* __restrict__ Wqf,
                                                    const float* __restrict__ boff,
                                                    const float* __restrict__ battn,
                                                    unsigned short* __restrict__ offbf,
                                                    float* __restrict__ attn) {
  __shared__ unsigned short Xs[32 * 256];
  const int t = threadIdx.x;
  const int w = t >> 6, lane = t & 63;
  const int lr = lane & 15, lgrp = lane >> 4;
  const long row0 = (long)blockIdx.x * 32;
  {
    const int r = t >> 3;
    const int c0 = (t & 7) * 32;
    const float* sp = &src[(row0 + r) * DD + c0];
    const float* pp = &pos[(row0 + r) * DD + c0];
#pragma unroll
    for (int j = 0; j < 4; ++j) {
      const float4 a = *reinterpret_cast<const float4*>(&sp[j * 8 + 0]);
      const float4 b = *reinterpret_cast<const float4*>(&sp[j * 8 + 4]);
      const float4 c = *reinterpret_cast<const float4*>(&pp[j * 8 + 0]);
      const float4 d = *reinterpret_cast<const float4*>(&pp[j * 8 + 4]);
      short8 pk;
      pk[0] = (short)f2bf(a.x + c.x); pk[1] = (short)f2bf(a.y + c.y);
      pk[2] = (short)f2bf(a.z + c.z); pk[3] = (short)f2bf(a.w + c.w);
      pk[4] = (short)f2bf(b.x + d.x); pk[5] = (short)f2bf(b.y + d.y);
      pk[6] = (short)f2bf(b.z + d.z); pk[7] = (short)f2bf(b.w + d.w);
      int byte = r * 512 + (c0 + j * 8) * 2;
      byte ^= (r & 7) << 4;
      *reinterpret_cast<short8*>(reinterpret_cast<char*>(Xs) + byte) = pk;
    }
  }
  __syncthreads();
  short8 af[2][8];
#pragma unroll
  for (int mt = 0; mt < 2; ++mt)
#pragma unroll
    for (int kt = 0; kt < 8; ++kt) {
      const int row = mt * 16 + lr;
      int byte = row * 512 + kt * 64 + lgrp * 16;
      byte ^= (row & 7) << 4;
      af[mt][kt] = *reinterpret_cast<const short8*>(reinterpret_cast<const char*>(Xs) + byte);
    }
  f32x4 acc[2][6];
#pragma unroll
  for (int mt = 0; mt < 2; ++mt)
#pragma unroll
    for (int i = 0; i < 6; ++i) acc[mt][i] = (f32x4){0.f, 0.f, 0.f, 0.f};
#pragma unroll
  for (int i = 0; i < 6; ++i) {
    const int ntg = w * 6 + i;
#pragma unroll
    for (int kt = 0; kt < 8; ++kt) {
      const short8 bf_ = *reinterpret_cast<const short8*>(&Wqf[((ntg * 8 + kt) * 64 + lane) * 8]);
#pragma unroll
      for (int mt = 0; mt < 2; ++mt)
        acc[mt][i] = __builtin_amdgcn_mfma_f32_16x16x32_bf16(af[mt][kt], bf_, acc[mt][i], 0, 0, 0);
    }
  }
#pragma unroll
  for (int i = 0; i < 6; ++i) {
    const int ntg = w * 6 + i;
    if (ntg < 16) {
      const int col = ntg * 16 + lr;
      const float bb = boff[col];
#pragma unroll
      for (int mt = 0; mt < 2; ++mt)
#pragma unroll
        for (int j = 0; j < 4; ++j) {
          const int row = mt * 16 + lgrp * 4 + j;
          offbf[(row0 + row) * 256 + col] = f2bf(acc[mt][i][j] + bb);
        }
    } else {
      const int na = ntg - 16;       // head index
      const float bb = battn[na * 16 + lr];
#pragma unroll
      for (int mt = 0; mt < 2; ++mt)
#pragma unroll
        for (int j = 0; j < 4; ++j) {
          const int row = mt * 16 + lgrp * 4 + j;
          const float v = acc[mt][i][j] + bb;
          float m = v;
#pragma unroll
          for (int d_ = 1; d_ <= 8; d_ <<= 1) m = fmaxf(m, __shfl_xor(m, d_, 16));
          const float e = __expf(v - m);
          float s = e;
#pragma unroll
          for (int d_ = 1; d_ <= 8; d_ <<= 1) s += __shfl_xor(s, d_, 16);
          attn[(row0 + row) * 128 + na * 16 + lr] = e / s;
        }
    }
  }
}

// ---------------------------------------------------------------------------
// K3: deformable sampling. XCD-image swizzle (per-XCD L2 slice 2.8MB < 4MB);
// SoA LDS: lane-linear writes (0 conflicts), broadcast/2-way reads (free).
// ---------------------------------------------------------------------------
__global__ __launch_bounds__(256) void k_sample3(const unsigned short* __restrict__ valbf,
                                                 const unsigned short* __restrict__ offbf,
                                                 const float* __restrict__ attn,
                                                 const float* __restrict__ refp,
                                                 unsigned short* __restrict__ src2bf) {
  __shared__ int   sIdx[4][2][4][64];
  __shared__ float sW  [4][2][4][64];
  const int t = threadIdx.x;
  const int w = t >> 6, lane = t & 63;
  const int hg = lane >> 3, li = lane & 7;
  const int B = blockIdx.x;
  const int bimg = (B & 7) >> 1;
  const int ii = ((B >> 3) << 1) + (B & 1);     // 0..1359
  const long n = (long)bimg * SLEN + ii * 4 + w;
  const long bOff = (long)bimg * SLEN;

  const int   WlA[4] = {64, 32, 16, 8};
  const float rWA[4] = {1.f / 64.f, 1.f / 32.f, 1.f / 16.f, 1.f / 8.f};
  const int   stA[4] = {0, 4096, 5120, 5376};

#pragma unroll
  for (int q = 0; q < 2; ++q) {
    const int pt = 2 * li + q;
    const int l = pt >> 2, p = pt & 3;
    const int Wi = WlA[l];
    const float Wf = (float)Wi, rW = rWA[l];
    const float rx = refp[(n * 4 + l) * 2 + 0];
    const float ry = refp[(n * 4 + l) * 2 + 1];
    const float aw = attn[n * 128 + hg * 16 + pt];
    const int oi = ((hg * 4 + l) * 4 + p) * 2;
    const unsigned int opk = *reinterpret_cast<const unsigned int*>(&offbf[n * 256 + oi]);
    const float ox = bf2f((unsigned short)(opk & 0xffff));
    const float oy = bf2f((unsigned short)(opk >> 16));
    const float px = (rx + ox * rW) * Wf - 0.5f;
    const float py = (ry + oy * rW) * Wf - 0.5f;
    const float x0f = floorf(px), y0f = floorf(py);
    const float fx = px - x0f, fy = py - y0f;
    const int x0 = (int)x0f, y0 = (int)y0f;
#pragma unroll
    for (int c = 0; c < 4; ++c) {
      const int dx = c & 1, dy = c >> 1;
      const int xi = x0 + dx, yi = y0 + dy;
      const float cw = (dx ? fx : 1.f - fx) * (dy ? fy : 1.f - fy);
      const bool valid = (xi >= 0) && (xi < Wi) && (yi >= 0) && (yi < Wi);
      const int xc = min(max(xi, 0), Wi - 1);
      const int yc = min(max(yi, 0), Wi - 1);
      const long flat = stA[l] + yc * Wi + xc;
      sIdx[w][q][c][lane] = (int)((bOff + flat) * DD + hg * DHD);
      sW[w][q][c][lane]   = aw * cw * (valid ? 1.f : 0.f);
    }
  }
  __syncthreads();

  float4 acc = make_float4(0.f, 0.f, 0.f, 0.f);
#pragma unroll 4
  for (int pt = 0; pt < 16; ++pt) {
    const int q = pt & 1;
    const int ls = hg * 8 + (pt >> 1);
    const int   i0 = sIdx[w][q][0][ls], i1 = sIdx[w][q][1][ls];
    const int   i2 = sIdx[w][q][2][ls], i3 = sIdx[w][q][3][ls];
    const float w0 = sW[w][q][0][ls], w1 = sW[w][q][1][ls];
    const float w2 = sW[w][q][2][ls], w3 = sW[w][q][3][ls];
    const ushort4v u0 = *reinterpret_cast<const ushort4v*>(&valbf[(long)i0 + li * 4]);
    const ushort4v u1 = *reinterpret_cast<const ushort4v*>(&valbf[(long)i1 + li * 4]);
    const ushort4v u2 = *reinterpret_cast<const ushort4v*>(&valbf[(long)i2 + li * 4]);
    const ushort4v u3 = *reinterpret_cast<const ushort4v*>(&valbf[(long)i3 + li * 4]);
    acc.x += w0 * bf2f(u0[0]) + w1 * bf2f(u1[0]) + w2 * bf2f(u2[0]) + w3 * bf2f(u3[0]);
    acc.y += w0 * bf2f(u0[1]) + w1 * bf2f(u1[1]) + w2 * bf2f(u2[1]) + w3 * bf2f(u3[1]);
    acc.z += w0 * bf2f(u0[2]) + w1 * bf2f(u1[2]) + w2 * bf2f(u2[2]) + w3 * bf2f(u3[2]);
    acc.w += w0 * bf2f(u0[3]) + w1 * bf2f(u1[3]) + w2 * bf2f(u2[3]) + w3 * bf2f(u3[3]);
  }
  ushort4v o;
  o[0] = f2bf(acc.x); o[1] = f2bf(acc.y); o[2] = f2bf(acc.z); o[3] = f2bf(acc.w);
  *reinterpret_cast<ushort4v*>(&src2bf[n * DD + hg * DHD + li * 4]) = o;
}

// ---------------------------------------------------------------------------
// K4: xbf = bf16(LN1(src + src2bf @ W_out + b_out)). (unchanged, proven)
// ---------------------------------------------------------------------------
__global__ __launch_bounds__(256) void k_outproj_mfma(const unsigned short* __restrict__ src2bf,
                                                      const unsigned short* __restrict__ Wof,
                                                      const float* __restrict__ bo,
                                                      const float* __restrict__ src,
                                                      const float* __restrict__ g1,
                                                      const float* __restrict__ b1g,
                                                      unsigned short* __restrict__ xbf) {
  __shared__ float rsum[32][4];
  __shared__ float rssq[32][4];
  const int t = threadIdx.x;
  const int w = t >> 6, lane = t & 63;
  const int lr = lane & 15, lgrp = lane >> 4;
  const long row0 = (long)blockIdx.x * 32;

  short8 af[2][8];
#pragma unroll
  for (int mt = 0; mt < 2; ++mt)
#pragma unroll
    for (int kt = 0; kt < 8; ++kt)
      af[mt][kt] = *reinterpret_cast<const short8*>(
          &src2bf[(row0 + mt * 16 + lr) * DD + kt * 32 + lgrp * 8]);

  f32x4 acc[2][4];
#pragma unroll
  for (int mt = 0; mt < 2; ++mt)
#pragma unroll
    for (int n = 0; n < 4; ++n) acc[mt][n] = (f32x4){0.f, 0.f, 0.f, 0.f};
#pragma unroll
  for (int n = 0; n < 4; ++n) {
    const int nt = w * 4 + n;
#pragma unroll
    for (int kt = 0; kt < 8; ++kt) {
      const short8 bf_ = *reinterpret_cast<const short8*>(&Wof[((nt * 8 + kt) * 64 + lane) * 8]);
#pragma unroll
      for (int mt = 0; mt < 2; ++mt)
        acc[mt][n] = __builtin_amdgcn_mfma_f32_16x16x32_bf16(af[mt][kt], bf_, acc[mt][n], 0, 0, 0);
    }
  }
  float bc[4], gc[4], bgc[4];
#pragma unroll
  for (int n = 0; n < 4; ++n) {
    const int col = w * 64 + n * 16 + lr;
    bc[n] = bo[col]; gc[n] = g1[col]; bgc[n] = b1g[col];
  }
  float vals[2][4][4];
#pragma unroll
  for (int mt = 0; mt < 2; ++mt)
#pragma unroll
    for (int j = 0; j < 4; ++j) {
      const int row = mt * 16 + lgrp * 4 + j;
      float s = 0.f, ss = 0.f;
#pragma unroll
      for (int n = 0; n < 4; ++n) {
        const int col = w * 64 + n * 16 + lr;
        const float v = acc[mt][n][j] + bc[n] + src[(row0 + row) * DD + col];
        vals[mt][n][j] = v;
        s += v; ss += v * v;
      }
#pragma unroll
      for (int m = 1; m <= 8; m <<= 1) { s += __shfl_xor(s, m, 64); ss += __shfl_xor(ss, m, 64); }
      if (lr == 0) { rsum[row][w] = s; rssq[row][w] = ss; }
    }
  __syncthreads();
#pragma unroll
  for (int mt = 0; mt < 2; ++mt)
#pragma unroll
    for (int j = 0; j < 4; ++j) {
      const int row = mt * 16 + lgrp * 4 + j;
      const float s  = rsum[row][0] + rsum[row][1] + rsum[row][2] + rsum[row][3];
      const float ss = rssq[row][0] + rssq[row][1] + rssq[row][2] + rssq[row][3];
      const float mean = s * (1.f / 256.f);
      const float inv  = rsqrtf(ss * (1.f / 256.f) - mean * mean + 1e-5f);
#pragma unroll
      for (int n = 0; n < 4; ++n) {
        const int col = w * 64 + n * 16 + lr;
        xbf[(row0 + row) * DD + col] = f2bf((vals[mt][n][j] - mean) * inv * gc[n] + bgc[n]);
      }
    }
}

// ---------------------------------------------------------------------------
// K5a: hbf = bf16(relu(xbf @ W1 + b1)), row-major, via SWAPPED-operand MFMA.
// Block = 64 tokens x 128 hdims, grid (340, 8) = 2720 blocks. A = W1f frag
// (-> W1^T), B = X row-major frag (direct global). C[m=hdim][n=token]: each
// lane holds 4 consecutive hdims -> packed 8B stores. No LDS, no barriers.
// ---------------------------------------------------------------------------
__global__ __launch_bounds__(256) void k_ffn1b(const unsigned short* __restrict__ xbf,
                                               const unsigned short* __restrict__ W1f,
                                               const float* __restrict__ b1v,
                                               unsigned short* __restrict__ hbf) {
  const int t = threadIdx.x;
  const int w = t >> 6, lane = t & 63;
  const int lr = lane & 15, lgrp = lane >> 4;
  const long row0 = (long)blockIdx.x * 64;
  const int hg = blockIdx.y;                // 128-hdim group (0..7)

  f32x4 acc[2][4];                          // [mm=hdim tile][n=token tile]
#pragma unroll
  for (int mm = 0; mm < 2; ++mm)
#pragma unroll
    for (int n = 0; n < 4; ++n) acc[mm][n] = (f32x4){0.f, 0.f, 0.f, 0.f};

#pragma unroll
  for (int kt = 0; kt < 8; ++kt) {
    short8 bx[4];
#pragma unroll
    for (int n = 0; n < 4; ++n)
      bx[n] = *reinterpret_cast<const short8*>(
          &xbf[(row0 + n * 16 + lr) * DD + kt * 32 + lgrp * 8]);
#pragma unroll
    for (int mm = 0; mm < 2; ++mm) {
      const int ntg = hg * 8 + w * 2 + mm;  // hdim tile (0..63)
      const short8 aw1 = *reinterpret_cast<const short8*>(&W1f[((ntg * 8 + kt) * 64 + lane) * 8]);
#pragma unroll
      for (int n = 0; n < 4; ++n)
        acc[mm][n] = __builtin_amdgcn_mfma_f32_16x16x32_bf16(aw1, bx[n], acc[mm][n], 0, 0, 0);
    }
  }

#pragma unroll
  for (int mm = 0; mm < 2; ++mm) {
    const int hd = hg * 128 + (w * 2 + mm) * 16 + lgrp * 4;   // global hdim base
    const float4 bq = *reinterpret_cast<const float4*>(&b1v[hd]);
#pragma unroll
    for (int n = 0; n < 4; ++n) {
      const long token = row0 + n * 16 + lr;
      int2 pk;
      pk.x = (int)pack2bf(fmaxf(acc[mm][n][0] + bq.x, 0.f),
                          fmaxf(acc[mm][n][1] + bq.y, 0.f));
      pk.y = (int)pack2bf(fmaxf(acc[mm][n][2] + bq.z, 0.f),
                          fmaxf(acc[mm][n][3] + bq.w, 0.f));
      *reinterpret_cast<int2*>(&hbf[token * DFF + hd]) = pk;
    }
  }
}

// ---------------------------------------------------------------------------
// K5b: out = LN2(xbf + hbf @ W2 + b2). Barrier-free K=1024 streaming loop,
// A-frags direct from row-major hbf; LN epilogue (1 barrier). (R4-proven)
// ---------------------------------------------------------------------------
__global__ __launch_bounds__(256) void k_ffn2(const unsigned short* __restrict__ hbf,
                                              const unsigned short* __restrict__ W2f,
                                              const float* __restrict__ b2v_,
                                              const unsigned short* __restrict__ xbf,
                                              const float* __restrict__ g2,
                                              const float* __restrict__ b2g,
                                              float* __restrict__ outp) {
  __shared__ float rsum[32][4];
  __shared__ float rssq[32][4];
  const int t = threadIdx.x;
  const int w = t >> 6, lane = t & 63;
  const int lr = lane & 15, lgrp = lane >> 4;
  const long row0 = (long)blockIdx.x * 32;

  f32x4 acc[2][4];
#pragma unroll
  for (int mt = 0; mt < 2; ++mt)
#pragma unroll
    for (int n = 0; n < 4; ++n) acc[mt][n] = (f32x4){0.f, 0.f, 0.f, 0.f};

#pragma unroll 4
  for (int kt = 0; kt < 32; ++kt) {
    short8 ha[2];
#pragma unroll
    for (int mt = 0; mt < 2; ++mt)
      ha[mt] = *reinterpret_cast<const short8*>(
          &hbf[(row0 + mt * 16 + lr) * DFF + kt * 32 + lgrp * 8]);
#pragma unroll
    for (int n = 0; n < 4; ++n) {
      const int nt = w * 4 + n;
      const short8 bf_ = *reinterpret_cast<const short8*>(&W2f[((nt * 32 + kt) * 64 + lane) * 8]);
#pragma unroll
      for (int mt = 0; mt < 2; ++mt)
        acc[mt][n] = __builtin_amdgcn_mfma_f32_16x16x32_bf16(ha[mt], bf_, acc[mt][n], 0, 0, 0);
    }
  }

  float b2c[4], g2c[4], bgc[4];
#pragma unroll
  for (int n = 0; n < 4; ++n) {
    const int col = w * 64 + n * 16 + lr;
    b2c[n] = b2v_[col]; g2c[n] = g2[col]; bgc[n] = b2g[col];
  }
  float vals[2][4][4];
#pragma unroll
  for (int mt = 0; mt < 2; ++mt)
#pragma unroll
    for (int j = 0; j < 4; ++j) {
      const int row = mt * 16 + lgrp * 4 + j;
      float s = 0.f, ss = 0.f;
#pragma unroll
      for (int n = 0; n < 4; ++n) {
        const int col = w * 64 + n * 16 + lr;
        const float v = acc[mt][n][j] + b2c[n] + bf2f(xbf[(row0 + row) * DD + col]);
        vals[mt][n][j] = v;
        s += v; ss += v * v;
      }
#pragma unroll
      for (int m = 1; m <= 8; m <<= 1) { s += __shfl_xor(s, m, 64); ss += __shfl_xor(ss, m, 64); }
      if (lr == 0) { rsum[row][w] = s; rssq[row][w] = ss; }
    }
  __syncthreads();
#pragma unroll
  for (int mt = 0; mt < 2; ++mt)
#pragma unroll
    for (int j = 0; j < 4; ++j) {
      const int row = mt * 16 + lgrp * 4 + j;
      const float s  = rsum[row][0] + rsum[row][1] + rsum[row][2] + rsum[row][3];
      const float ss = rssq[row][0] + rssq[row][1] + rssq[row][2] + rssq[row][3];
      const float mean = s * (1.f / 256.f);
      const float inv  = rsqrtf(ss * (1.f / 256.f) - mean * mean + 1e-5f);
#pragma unroll
      for (int n = 0; n < 4; ++n) {
        const int col = w * 64 + n * 16 + lr;
        outp[(row0 + row) * DD + col] = (vals[mt][n][j] - mean) * inv * g2c[n] + bgc[n];
      }
    }
}

extern "C" void kernel_launch(void* const* d_in, const int* in_sizes, int n_in,
                              void* d_out, int out_size, void* d_ws, size_t ws_size,
                              hipStream_t stream) {
  const float* src  = (const float*)d_in[0];
  const float* refp = (const float*)d_in[1];
  const float* pos  = (const float*)d_in[5];
  const float* Wv   = (const float*)d_in[6];
  const float* bv   = (const float*)d_in[7];
  const float* Woff = (const float*)d_in[8];
  const float* boff = (const float*)d_in[9];
  const float* Wat  = (const float*)d_in[10];
  const float* bat  = (const float*)d_in[11];
  const float* Wo   = (const float*)d_in[12];
  const float* bo   = (const float*)d_in[13];
  const float* g1   = (const float*)d_in[14];
  const float* b1g  = (const float*)d_in[15];
  const float* W1   = (const float*)d_in[16];
  const float* b1f  = (const float*)d_in[17];
  const float* W2   = (const float*)d_in[18];
  const float* b2f  = (const float*)d_in[19];
  const float* g2   = (const float*)d_in[20];
  const float* b2g  = (const float*)d_in[21];
  float* out = (float*)d_out;

  // workspace (~57.2 MB):
  // [valbf | offbf | attn(f32) | src2bf] = exactly NTOK*2048 B, aliased by hbf
  // (all four dead before k_ffn1b writes hbf). Then xbf, then weight frags.
  unsigned short* valbf  = (unsigned short*)d_ws;       // NTOK*256 u16
  unsigned short* offbf  = valbf + NTOK * 256;          // NTOK*256 u16
  float*          attn   = (float*)(offbf + NTOK * 256);// NTOK*128 f32
  unsigned short* src2bf = (unsigned short*)(attn + NTOK * 128); // NTOK*256 u16
  unsigned short* hbf    = (unsigned short*)d_ws;       // NTOK*1024 u16 (alias)
  unsigned short* xbf    = src2bf + NTOK * 256;         // NTOK*256 u16
  unsigned short* W1f = xbf + NTOK * 256;               // 262144
  unsigned short* W2f = W1f + 262144;                   // 262144
  unsigned short* Wvf = W2f + 262144;                   // 65536
  unsigned short* Wqf = Wvf + 65536;                    // 98304
  unsigned short* Wof = Wqf + 98304;                    // 65536

  hipLaunchKernelGGL(k_prep_all, dim3(2944), dim3(256), 0, stream,
                     W1, W2, Wv, Woff, Wat, Wo, W1f, W2f, Wvf, Wqf, Wof);
  hipLaunchKernelGGL(k_value_mfma, dim3((int)(NTOK / 32)), dim3(256), 0, stream,
                     src, Wvf, bv, valbf);
  hipLaunchKernelGGL(k_qproj_mfma, dim3((int)(NTOK / 32)), dim3(256), 0, stream,
                     src, pos, Wqf, boff, bat, offbf, attn);
  hipLaunchKernelGGL(k_sample3, dim3((int)(NTOK / 4)), dim3(256), 0, stream,
                     valbf, offbf, attn, refp, src2bf);
  hipLaunchKernelGGL(k_outproj_mfma, dim3((int)(NTOK / 32)), dim3(256), 0, stream,
                     src2bf, Wof, bo, src, g1, b1g, xbf);
  hipLaunchKernelGGL(k_ffn1b, dim3((int)(NTOK / 64), 8), dim3(256), 0, stream,
                     xbf, W1f, b1f, hbf);
  hipLaunchKernelGGL(k_ffn2, dim3((int)(NTOK / 32)), dim3(256), 0, stream,
                     hbf, W2f, b2f, xbf, g2, b2g, out);
}

// Round 8
// 206.440 us; speedup vs baseline: 1.2991x; 1.0328x over previous
//
#include <hip/hip_runtime.h>

// Problem constants (fixed by setup_inputs)
constexpr int NB   = 4;
constexpr int SLEN = 5440;           // 64*64 + 32*32 + 16*16 + 8*8
constexpr long NTOK = (long)NB * SLEN; // 21760
constexpr int DD   = 256;
constexpr int NH   = 8;
constexpr int DHD  = 32;
constexpr int NL   = 4;
constexpr int NP   = 4;
constexpr int DFF  = 1024;

typedef __attribute__((ext_vector_type(8))) short short8;   // 8 x bf16
typedef __attribute__((ext_vector_type(4))) float f32x4;
typedef __attribute__((ext_vector_type(4))) unsigned short ushort4v;

static __device__ __forceinline__ unsigned short f2bf(float x) {
  union { float f; unsigned int u; } v; v.f = x;
  unsigned int r = v.u + 0x7fffu + ((v.u >> 16) & 1u);   // RNE
  return (unsigned short)(r >> 16);
}
static __device__ __forceinline__ float bf2f(unsigned short u) {
  union { unsigned int i; float f; } v; v.i = ((unsigned int)u) << 16; return v.f;
}
static __device__ __forceinline__ unsigned int pack2bf(float lo, float hi) {
  return (unsigned int)f2bf(lo) | ((unsigned int)f2bf(hi) << 16);
}

// B-fragment position for mfma_f32_16x16x32_bf16, weight K x N row-major.
// tile (kt,nt): lane l holds B[kt*32 + (l>>4)*8 + i][nt*16 + (l&15)], i=0..7
// Dual-use: same registers read as the A-fragment give A = W^T (swapped-op).
static __device__ __forceinline__ long fragpos(int k, int n, int KT) {
  const int kt = k >> 5, i = k & 7;
  const int lane = ((k >> 3) & 3) * 16 + (n & 15);
  const int nt = n >> 4;
  return (((long)(nt * KT + kt) * 64 + lane) * 8 + i);
}

// ---------------------------------------------------------------------------
// K_prep_all: fragment W1, W2, Wv, [Woff|Wattn], Wo into bf16 MFMA layout.
// ---------------------------------------------------------------------------
__global__ __launch_bounds__(256) void k_prep_all(const float* __restrict__ W1,
                                                  const float* __restrict__ W2,
                                                  const float* __restrict__ Wv,
                                                  const float* __restrict__ Woff,
                                                  const float* __restrict__ Wattn,
                                                  const float* __restrict__ Wo,
                                                  unsigned short* __restrict__ W1f,
                                                  unsigned short* __restrict__ W2f,
                                                  unsigned short* __restrict__ Wvf,
                                                  unsigned short* __restrict__ Wqf,
                                                  unsigned short* __restrict__ Wof) {
  const int g = blockIdx.x * 256 + threadIdx.x;
  if (g < 262144) {                       // W1: 256 x 1024, KT=8
    const int k = g >> 10, n = g & 1023;
    W1f[fragpos(k, n, 8)] = f2bf(W1[g]);
  } else if (g < 524288) {                // W2: 1024 x 256, KT=32
    const int g2 = g - 262144;
    const int k = g2 >> 8, n = g2 & 255;
    W2f[fragpos(k, n, 32)] = f2bf(W2[g2]);
  } else if (g < 589824) {                // Wv: 256 x 256, KT=8
    const int g2 = g - 524288;
    const int k = g2 >> 8, n = g2 & 255;
    Wvf[fragpos(k, n, 8)] = f2bf(Wv[g2]);
  } else if (g < 688128) {                // Wq fused: 256 x 384 (=256 off + 128 attn)
    const int g2 = g - 589824;
    const int k = g2 / 384, n = g2 % 384;
    const float w = (n < 256) ? Woff[k * 256 + n] : Wattn[k * 128 + (n - 256)];
    Wqf[fragpos(k, n, 8)] = f2bf(w);
  } else if (g < 753664) {                // Wo: 256 x 256
    const int g2 = g - 688128;
    const int k = g2 >> 8, n = g2 & 255;
    Wof[fragpos(k, n, 8)] = f2bf(Wo[g2]);
  }
}

// ---------------------------------------------------------------------------
// K1: value(bf16) = src @ W_value + b_value. (unchanged, proven)
// ---------------------------------------------------------------------------
__global__ __launch_bounds__(256) void k_value_mfma(const float* __restrict__ src,
                                                    const unsigned short* __restrict__ Wvf,
                                                    const float* __restrict__ bv,
                                                    unsigned short* __restrict__ valbf) {
  __shared__ unsigned short Xs[32 * 256];
  const int t = threadIdx.x;
  const int w = t >> 6, lane = t & 63;
  const int lr = lane & 15, lgrp = lane >> 4;
  const long row0 = (long)blockIdx.x * 32;
  {
    const int r = t >> 3;
    const int c0 = (t & 7) * 32;
    const float* srcp = &src[(row0 + r) * DD + c0];
#pragma unroll
    for (int j = 0; j < 4; ++j) {
      const float4 a = *reinterpret_cast<const float4*>(&srcp[j * 8 + 0]);
      const float4 b = *reinterpret_cast<const float4*>(&srcp[j * 8 + 4]);
      short8 pk;
      pk[0] = (short)f2bf(a.x); pk[1] = (short)f2bf(a.y);
      pk[2] = (short)f2bf(a.z); pk[3] = (short)f2bf(a.w);
      pk[4] = (short)f2bf(b.x); pk[5] = (short)f2bf(b.y);
      pk[6] = (short)f2bf(b.z); pk[7] = (short)f2bf(b.w);
      int byte = r * 512 + (c0 + j * 8) * 2;
      byte ^= (r & 7) << 4;
      *reinterpret_cast<short8*>(reinterpret_cast<char*>(Xs) + byte) = pk;
    }
  }
  __syncthreads();
  short8 af[2][8];
#pragma unroll
  for (int mt = 0; mt < 2; ++mt)
#pragma unroll
    for (int kt = 0; kt < 8; ++kt) {
      const int row = mt * 16 + lr;
      int byte = row * 512 + kt * 64 + lgrp * 16;
      byte ^= (row & 7) << 4;
      af[mt][kt] = *reinterpret_cast<const short8*>(reinterpret_cast<const char*>(Xs) + byte);
    }
  f32x4 acc[2][4];
#pragma unroll
  for (int mt = 0; mt < 2; ++mt)
#pragma unroll
    for (int n = 0; n < 4; ++n) acc[mt][n] = (f32x4){0.f, 0.f, 0.f, 0.f};
#pragma unroll
  for (int n = 0; n < 4; ++n) {
    const int nt = w * 4 + n;
#pragma unroll
    for (int kt = 0; kt < 8; ++kt) {
      const short8 bf_ = *reinterpret_cast<const short8*>(&Wvf[((nt * 8 + kt) * 64 + lane) * 8]);
#pragma unroll
      for (int mt = 0; mt < 2; ++mt)
        acc[mt][n] = __builtin_amdgcn_mfma_f32_16x16x32_bf16(af[mt][kt], bf_, acc[mt][n], 0, 0, 0);
    }
  }
#pragma unroll
  for (int n = 0; n < 4; ++n) {
    const int col = w * 64 + n * 16 + lr;
    const float bb = bv[col];
#pragma unroll
    for (int mt = 0; mt < 2; ++mt)
#pragma unroll
      for (int j = 0; j < 4; ++j) {
        const int row = mt * 16 + lgrp * 4 + j;
        valbf[(row0 + row) * DD + col] = f2bf(acc[mt][n][j] + bb);
      }
  }
}

// ---------------------------------------------------------------------------
// K2: q = src+pos; off(bf16) = q@W_off+b_off; attn(f32) = softmax16(...).
// ---------------------------------------------------------------------------
__global__ __launch_bounds__(256) void k_qproj_mfma(const float* __restrict__ src,
                                                    const float* __restrict__ pos,
                                                    const unsigned short* __restrict__ Wqf,
                                                    const float* __restrict__ boff,
                                                    const float* __restrict__ battn,
                                                    unsigned short* __restrict__ offbf,
                                                    float* __restrict__ attn) {
  __shared__ unsigned short Xs[32 * 256];
  const int t = threadIdx.x;
  const int w = t >> 6, lane = t & 63;
  const int lr = lane & 15, lgrp = lane >> 4;
  const long row0 = (long)blockIdx.x * 32;
  {
    const int r = t >> 3;
    const int c0 = (t & 7) * 32;
    const float* sp = &src[(row0 + r) * DD + c0];
    const float* pp = &pos[(row0 + r) * DD + c0];
#pragma unroll
    for (int j = 0; j < 4; ++j) {
      const float4 a = *reinterpret_cast<const float4*>(&sp[j * 8 + 0]);
      const float4 b = *reinterpret_cast<const float4*>(&sp[j * 8 + 4]);
      const float4 c = *reinterpret_cast<const float4*>(&pp[j * 8 + 0]);
      const float4 d = *reinterpret_cast<const float4*>(&pp[j * 8 + 4]);
      short8 pk;
      pk[0] = (short)f2bf(a.x + c.x); pk[1] = (short)f2bf(a.y + c.y);
      pk[2] = (short)f2bf(a.z + c.z); pk[3] = (short)f2bf(a.w + c.w);
      pk[4] = (short)f2bf(b.x + d.x); pk[5] = (short)f2bf(b.y + d.y);
      pk[6] = (short)f2bf(b.z + d.z); pk[7] = (short)f2bf(b.w + d.w);
      int byte = r * 512 + (c0 + j * 8) * 2;
      byte ^= (r & 7) << 4;
      *reinterpret_cast<short8*>(reinterpret_cast<char*>(Xs) + byte) = pk;
    }
  }
  __syncthreads();
  short8 af[2][8];
#pragma unroll
  for (int mt = 0; mt < 2; ++mt)
#pragma unroll
    for (int kt = 0; kt < 8; ++kt) {
      const int row = mt * 16 + lr;
      int byte = row * 512 + kt * 64 + lgrp * 16;
      byte ^= (row & 7) << 4;
      af[mt][kt] = *reinterpret_cast<const short8*>(reinterpret_cast<const char*>(Xs) + byte);
    }
  f32x4 acc[2][6];
#pragma unroll
  for (int mt = 0; mt < 2; ++mt)
#pragma unroll
    for (int i = 0; i < 6; ++i) acc[mt][i] = (f32x4){0.f, 0.f, 0.f, 0.f};
#pragma unroll
  for (int i = 0; i < 6; ++i) {
    const int ntg = w * 6 + i;
#pragma unroll
    for (int kt = 0; kt < 8; ++kt) {
      const short8 bf_ = *reinterpret_cast<const short8*>(&Wqf[((ntg * 8 + kt) * 64 + lane) * 8]);
#pragma unroll
      for (int mt = 0; mt < 2; ++mt)
        acc[mt][i] = __builtin_amdgcn_mfma_f32_16x16x32_bf16(af[mt][kt], bf_, acc[mt][i], 0, 0, 0);
    }
  }
#pragma unroll
  for (int i = 0; i < 6; ++i) {
    const int ntg = w * 6 + i;
    if (ntg < 16) {
      const int col = ntg * 16 + lr;
      const float bb = boff[col];
#pragma unroll
      for (int mt = 0; mt < 2; ++mt)
#pragma unroll
        for (int j = 0; j < 4; ++j) {
          const int row = mt * 16 + lgrp * 4 + j;
          offbf[(row0 + row) * 256 + col] = f2bf(acc[mt][i][j] + bb);
        }
    } else {
      const int na = ntg - 16;       // head index
      const float bb = battn[na * 16 + lr];
#pragma unroll
      for (int mt = 0; mt < 2; ++mt)
#pragma unroll
        for (int j = 0; j < 4; ++j) {
          const int row = mt * 16 + lgrp * 4 + j;
          const float v = acc[mt][i][j] + bb;
          float m = v;
#pragma unroll
          for (int d_ = 1; d_ <= 8; d_ <<= 1) m = fmaxf(m, __shfl_xor(m, d_, 16));
          const float e = __expf(v - m);
          float s = e;
#pragma unroll
          for (int d_ = 1; d_ <= 8; d_ <<= 1) s += __shfl_xor(s, d_, 16);
          attn[(row0 + row) * 128 + na * 16 + lr] = e / s;
        }
    }
  }
}

// ---------------------------------------------------------------------------
// K3: deformable sampling. XCD-image swizzle (per-XCD L2 slice 2.8MB < 4MB);
// SoA LDS: lane-linear writes (0 conflicts), broadcast/2-way reads (free).
// ---------------------------------------------------------------------------
__global__ __launch_bounds__(256) void k_sample3(const unsigned short* __restrict__ valbf,
                                                 const unsigned short* __restrict__ offbf,
                                                 const float* __restrict__ attn,
                                                 const float* __restrict__ refp,
                                                 unsigned short* __restrict__ src2bf) {
  __shared__ int   sIdx[4][2][4][64];
  __shared__ float sW  [4][2][4][64];
  const int t = threadIdx.x;
  const int w = t >> 6, lane = t & 63;
  const int hg = lane >> 3, li = lane & 7;
  const int B = blockIdx.x;
  const int bimg = (B & 7) >> 1;
  const int ii = ((B >> 3) << 1) + (B & 1);     // 0..1359
  const long n = (long)bimg * SLEN + ii * 4 + w;
  const long bOff = (long)bimg * SLEN;

  const int   WlA[4] = {64, 32, 16, 8};
  const float rWA[4] = {1.f / 64.f, 1.f / 32.f, 1.f / 16.f, 1.f / 8.f};
  const int   stA[4] = {0, 4096, 5120, 5376};

#pragma unroll
  for (int q = 0; q < 2; ++q) {
    const int pt = 2 * li + q;
    const int l = pt >> 2, p = pt & 3;
    const int Wi = WlA[l];
    const float Wf = (float)Wi, rW = rWA[l];
    const float rx = refp[(n * 4 + l) * 2 + 0];
    const float ry = refp[(n * 4 + l) * 2 + 1];
    const float aw = attn[n * 128 + hg * 16 + pt];
    const int oi = ((hg * 4 + l) * 4 + p) * 2;
    const unsigned int opk = *reinterpret_cast<const unsigned int*>(&offbf[n * 256 + oi]);
    const float ox = bf2f((unsigned short)(opk & 0xffff));
    const float oy = bf2f((unsigned short)(opk >> 16));
    const float px = (rx + ox * rW) * Wf - 0.5f;
    const float py = (ry + oy * rW) * Wf - 0.5f;
    const float x0f = floorf(px), y0f = floorf(py);
    const float fx = px - x0f, fy = py - y0f;
    const int x0 = (int)x0f, y0 = (int)y0f;
#pragma unroll
    for (int c = 0; c < 4; ++c) {
      const int dx = c & 1, dy = c >> 1;
      const int xi = x0 + dx, yi = y0 + dy;
      const float cw = (dx ? fx : 1.f - fx) * (dy ? fy : 1.f - fy);
      const bool valid = (xi >= 0) && (xi < Wi) && (yi >= 0) && (yi < Wi);
      const int xc = min(max(xi, 0), Wi - 1);
      const int yc = min(max(yi, 0), Wi - 1);
      const long flat = stA[l] + yc * Wi + xc;
      sIdx[w][q][c][lane] = (int)((bOff + flat) * DD + hg * DHD);
      sW[w][q][c][lane]   = aw * cw * (valid ? 1.f : 0.f);
    }
  }
  __syncthreads();

  float4 acc = make_float4(0.f, 0.f, 0.f, 0.f);
#pragma unroll 4
  for (int pt = 0; pt < 16; ++pt) {
    const int q = pt & 1;
    const int ls = hg * 8 + (pt >> 1);
    const int   i0 = sIdx[w][q][0][ls], i1 = sIdx[w][q][1][ls];
    const int   i2 = sIdx[w][q][2][ls], i3 = sIdx[w][q][3][ls];
    const float w0 = sW[w][q][0][ls], w1 = sW[w][q][1][ls];
    const float w2 = sW[w][q][2][ls], w3 = sW[w][q][3][ls];
    const ushort4v u0 = *reinterpret_cast<const ushort4v*>(&valbf[(long)i0 + li * 4]);
    const ushort4v u1 = *reinterpret_cast<const ushort4v*>(&valbf[(long)i1 + li * 4]);
    const ushort4v u2 = *reinterpret_cast<const ushort4v*>(&valbf[(long)i2 + li * 4]);
    const ushort4v u3 = *reinterpret_cast<const ushort4v*>(&valbf[(long)i3 + li * 4]);
    acc.x += w0 * bf2f(u0[0]) + w1 * bf2f(u1[0]) + w2 * bf2f(u2[0]) + w3 * bf2f(u3[0]);
    acc.y += w0 * bf2f(u0[1]) + w1 * bf2f(u1[1]) + w2 * bf2f(u2[1]) + w3 * bf2f(u3[1]);
    acc.z += w0 * bf2f(u0[2]) + w1 * bf2f(u1[2]) + w2 * bf2f(u2[2]) + w3 * bf2f(u3[2]);
    acc.w += w0 * bf2f(u0[3]) + w1 * bf2f(u1[3]) + w2 * bf2f(u2[3]) + w3 * bf2f(u3[3]);
  }
  ushort4v o;
  o[0] = f2bf(acc.x); o[1] = f2bf(acc.y); o[2] = f2bf(acc.z); o[3] = f2bf(acc.w);
  *reinterpret_cast<ushort4v*>(&src2bf[n * DD + hg * DHD + li * 4]) = o;
}

// ---------------------------------------------------------------------------
// K4: xbf = bf16(LN1(src + src2bf @ W_out + b_out)). (unchanged, proven)
// ---------------------------------------------------------------------------
__global__ __launch_bounds__(256) void k_outproj_mfma(const unsigned short* __restrict__ src2bf,
                                                      const unsigned short* __restrict__ Wof,
                                                      const float* __restrict__ bo,
                                                      const float* __restrict__ src,
                                                      const float* __restrict__ g1,
                                                      const float* __restrict__ b1g,
                                                      unsigned short* __restrict__ xbf) {
  __shared__ float rsum[32][4];
  __shared__ float rssq[32][4];
  const int t = threadIdx.x;
  const int w = t >> 6, lane = t & 63;
  const int lr = lane & 15, lgrp = lane >> 4;
  const long row0 = (long)blockIdx.x * 32;

  short8 af[2][8];
#pragma unroll
  for (int mt = 0; mt < 2; ++mt)
#pragma unroll
    for (int kt = 0; kt < 8; ++kt)
      af[mt][kt] = *reinterpret_cast<const short8*>(
          &src2bf[(row0 + mt * 16 + lr) * DD + kt * 32 + lgrp * 8]);

  f32x4 acc[2][4];
#pragma unroll
  for (int mt = 0; mt < 2; ++mt)
#pragma unroll
    for (int n = 0; n < 4; ++n) acc[mt][n] = (f32x4){0.f, 0.f, 0.f, 0.f};
#pragma unroll
  for (int n = 0; n < 4; ++n) {
    const int nt = w * 4 + n;
#pragma unroll
    for (int kt = 0; kt < 8; ++kt) {
      const short8 bf_ = *reinterpret_cast<const short8*>(&Wof[((nt * 8 + kt) * 64 + lane) * 8]);
#pragma unroll
      for (int mt = 0; mt < 2; ++mt)
        acc[mt][n] = __builtin_amdgcn_mfma_f32_16x16x32_bf16(af[mt][kt], bf_, acc[mt][n], 0, 0, 0);
    }
  }
  float bc[4], gc[4], bgc[4];
#pragma unroll
  for (int n = 0; n < 4; ++n) {
    const int col = w * 64 + n * 16 + lr;
    bc[n] = bo[col]; gc[n] = g1[col]; bgc[n] = b1g[col];
  }
  float vals[2][4][4];
#pragma unroll
  for (int mt = 0; mt < 2; ++mt)
#pragma unroll
    for (int j = 0; j < 4; ++j) {
      const int row = mt * 16 + lgrp * 4 + j;
      float s = 0.f, ss = 0.f;
#pragma unroll
      for (int n = 0; n < 4; ++n) {
        const int col = w * 64 + n * 16 + lr;
        const float v = acc[mt][n][j] + bc[n] + src[(row0 + row) * DD + col];
        vals[mt][n][j] = v;
        s += v; ss += v * v;
      }
#pragma unroll
      for (int m = 1; m <= 8; m <<= 1) { s += __shfl_xor(s, m, 64); ss += __shfl_xor(ss, m, 64); }
      if (lr == 0) { rsum[row][w] = s; rssq[row][w] = ss; }
    }
  __syncthreads();
#pragma unroll
  for (int mt = 0; mt < 2; ++mt)
#pragma unroll
    for (int j = 0; j < 4; ++j) {
      const int row = mt * 16 + lgrp * 4 + j;
      const float s  = rsum[row][0] + rsum[row][1] + rsum[row][2] + rsum[row][3];
      const float ss = rssq[row][0] + rssq[row][1] + rssq[row][2] + rssq[row][3];
      const float mean = s * (1.f / 256.f);
      const float inv  = rsqrtf(ss * (1.f / 256.f) - mean * mean + 1e-5f);
#pragma unroll
      for (int n = 0; n < 4; ++n) {
        const int col = w * 64 + n * 16 + lr;
        xbf[(row0 + row) * DD + col] = f2bf((vals[mt][n][j] - mean) * inv * gc[n] + bgc[n]);
      }
    }
}

// ---------------------------------------------------------------------------
// K5a: hbf = bf16(relu(xbf @ W1 + b1)), row-major, swapped-operand MFMA.
// DENSE variant: wave-tile = 64 tokens x 128 hdims, acc = 32 f32x4 (128 VGPR),
// per kt-step 12 loads : 32 MFMAs (2.7:1). Grid (340, 2), no LDS, no barriers.
// ---------------------------------------------------------------------------
__global__ __launch_bounds__(256) void k_ffn1c(const unsigned short* __restrict__ xbf,
                                               const unsigned short* __restrict__ W1f,
                                               const float* __restrict__ b1v,
                                               unsigned short* __restrict__ hbf) {
  const int t = threadIdx.x;
  const int w = t >> 6, lane = t & 63;
  const int lr = lane & 15, lgrp = lane >> 4;
  const long row0 = (long)blockIdx.x * 64;
  const int hg = blockIdx.y;                // 512-hdim half (0..1)

  f32x4 acc[8][4];                          // [mm=hdim tile][n=token tile]
#pragma unroll
  for (int mm = 0; mm < 8; ++mm)
#pragma unroll
    for (int n = 0; n < 4; ++n) acc[mm][n] = (f32x4){0.f, 0.f, 0.f, 0.f};

#pragma unroll
  for (int kt = 0; kt < 8; ++kt) {
    short8 bx[4];
#pragma unroll
    for (int n = 0; n < 4; ++n)
      bx[n] = *reinterpret_cast<const short8*>(
          &xbf[(row0 + n * 16 + lr) * DD + kt * 32 + lgrp * 8]);
#pragma unroll
    for (int mm = 0; mm < 8; ++mm) {
      const int ntg = hg * 32 + w * 8 + mm;  // hdim tile (0..63)
      const short8 aw1 = *reinterpret_cast<const short8*>(&W1f[((ntg * 8 + kt) * 64 + lane) * 8]);
#pragma unroll
      for (int n = 0; n < 4; ++n)
        acc[mm][n] = __builtin_amdgcn_mfma_f32_16x16x32_bf16(aw1, bx[n], acc[mm][n], 0, 0, 0);
    }
  }

#pragma unroll
  for (int mm = 0; mm < 8; ++mm) {
    const int hd = hg * 512 + (w * 8 + mm) * 16 + lgrp * 4;   // global hdim base
    const float4 bq = *reinterpret_cast<const float4*>(&b1v[hd]);
#pragma unroll
    for (int n = 0; n < 4; ++n) {
      const long token = row0 + n * 16 + lr;
      int2 pk;
      pk.x = (int)pack2bf(fmaxf(acc[mm][n][0] + bq.x, 0.f),
                          fmaxf(acc[mm][n][1] + bq.y, 0.f));
      pk.y = (int)pack2bf(fmaxf(acc[mm][n][2] + bq.z, 0.f),
                          fmaxf(acc[mm][n][3] + bq.w, 0.f));
      *reinterpret_cast<int2*>(&hbf[token * DFF + hd]) = pk;
    }
  }
}

// ---------------------------------------------------------------------------
// K5b: out = LN2(xbf + hbf @ W2 + b2). Barrier-free K=1024 streaming loop,
// A-frags direct from row-major hbf; LN epilogue (1 barrier). (R4-proven)
// ---------------------------------------------------------------------------
__global__ __launch_bounds__(256) void k_ffn2(const unsigned short* __restrict__ hbf,
                                              const unsigned short* __restrict__ W2f,
                                              const float* __restrict__ b2v_,
                                              const unsigned short* __restrict__ xbf,
                                              const float* __restrict__ g2,
                                              const float* __restrict__ b2g,
                                              float* __restrict__ outp) {
  __shared__ float rsum[32][4];
  __shared__ float rssq[32][4];
  const int t = threadIdx.x;
  const int w = t >> 6, lane = t & 63;
  const int lr = lane & 15, lgrp = lane >> 4;
  const long row0 = (long)blockIdx.x * 32;

  f32x4 acc[2][4];
#pragma unroll
  for (int mt = 0; mt < 2; ++mt)
#pragma unroll
    for (int n = 0; n < 4; ++n) acc[mt][n] = (f32x4){0.f, 0.f, 0.f, 0.f};

#pragma unroll 4
  for (int kt = 0; kt < 32; ++kt) {
    short8 ha[2];
#pragma unroll
    for (int mt = 0; mt < 2; ++mt)
      ha[mt] = *reinterpret_cast<const short8*>(
          &hbf[(row0 + mt * 16 + lr) * DFF + kt * 32 + lgrp * 8]);
#pragma unroll
    for (int n = 0; n < 4; ++n) {
      const int nt = w * 4 + n;
      const short8 bf_ = *reinterpret_cast<const short8*>(&W2f[((nt * 32 + kt) * 64 + lane) * 8]);
#pragma unroll
      for (int mt = 0; mt < 2; ++mt)
        acc[mt][n] = __builtin_amdgcn_mfma_f32_16x16x32_bf16(ha[mt], bf_, acc[mt][n], 0, 0, 0);
    }
  }

  float b2c[4], g2c[4], bgc[4];
#pragma unroll
  for (int n = 0; n < 4; ++n) {
    const int col = w * 64 + n * 16 + lr;
    b2c[n] = b2v_[col]; g2c[n] = g2[col]; bgc[n] = b2g[col];
  }
  float vals[2][4][4];
#pragma unroll
  for (int mt = 0; mt < 2; ++mt)
#pragma unroll
    for (int j = 0; j < 4; ++j) {
      const int row = mt * 16 + lgrp * 4 + j;
      float s = 0.f, ss = 0.f;
#pragma unroll
      for (int n = 0; n < 4; ++n) {
        const int col = w * 64 + n * 16 + lr;
        const float v = acc[mt][n][j] + b2c[n] + bf2f(xbf[(row0 + row) * DD + col]);
        vals[mt][n][j] = v;
        s += v; ss += v * v;
      }
#pragma unroll
      for (int m = 1; m <= 8; m <<= 1) { s += __shfl_xor(s, m, 64); ss += __shfl_xor(ss, m, 64); }
      if (lr == 0) { rsum[row][w] = s; rssq[row][w] = ss; }
    }
  __syncthreads();
#pragma unroll
  for (int mt = 0; mt < 2; ++mt)
#pragma unroll
    for (int j = 0; j < 4; ++j) {
      const int row = mt * 16 + lgrp * 4 + j;
      const float s  = rsum[row][0] + rsum[row][1] + rsum[row][2] + rsum[row][3];
      const float ss = rssq[row][0] + rssq[row][1] + rssq[row][2] + rssq[row][3];
      const float mean = s * (1.f / 256.f);
      const float inv  = rsqrtf(ss * (1.f / 256.f) - mean * mean + 1e-5f);
#pragma unroll
      for (int n = 0; n < 4; ++n) {
        const int col = w * 64 + n * 16 + lr;
        outp[(row0 + row) * DD + col] = (vals[mt][n][j] - mean) * inv * g2c[n] + bgc[n];
      }
    }
}

extern "C" void kernel_launch(void* const* d_in, const int* in_sizes, int n_in,
                              void* d_out, int out_size, void* d_ws, size_t ws_size,
                              hipStream_t stream) {
  const float* src  = (const float*)d_in[0];
  const float* refp = (const float*)d_in[1];
  const float* pos  = (const float*)d_in[5];
  const float* Wv   = (const float*)d_in[6];
  const float* bv   = (const float*)d_in[7];
  const float* Woff = (const float*)d_in[8];
  const float* boff = (const float*)d_in[9];
  const float* Wat  = (const float*)d_in[10];
  const float* bat  = (const float*)d_in[11];
  const float* Wo   = (const float*)d_in[12];
  const float* bo   = (const float*)d_in[13];
  const float* g1   = (const float*)d_in[14];
  const float* b1g  = (const float*)d_in[15];
  const float* W1   = (const float*)d_in[16];
  const float* b1f  = (const float*)d_in[17];
  const float* W2   = (const float*)d_in[18];
  const float* b2f  = (const float*)d_in[19];
  const float* g2   = (const float*)d_in[20];
  const float* b2g  = (const float*)d_in[21];
  float* out = (float*)d_out;

  // workspace (~57.2 MB):
  // [valbf | offbf | attn(f32) | src2bf] = exactly NTOK*2048 B, aliased by hbf
  // (all four dead before k_ffn1c writes hbf). Then xbf, then weight frags.
  unsigned short* valbf  = (unsigned short*)d_ws;       // NTOK*256 u16
  unsigned short* offbf  = valbf + NTOK * 256;          // NTOK*256 u16
  float*          attn   = (float*)(offbf + NTOK * 256);// NTOK*128 f32
  unsigned short* src2bf = (unsigned short*)(attn + NTOK * 128); // NTOK*256 u16
  unsigned short* hbf    = (unsigned short*)d_ws;       // NTOK*1024 u16 (alias)
  unsigned short* xbf    = src2bf + NTOK * 256;         // NTOK*256 u16
  unsigned short* W1f = xbf + NTOK * 256;               // 262144
  unsigned short* W2f = W1f + 262144;                   // 262144
  unsigned short* Wvf = W2f + 262144;                   // 65536
  unsigned short* Wqf = Wvf + 65536;                    // 98304
  unsigned short* Wof = Wqf + 98304;                    // 65536

  hipLaunchKernelGGL(k_prep_all, dim3(2944), dim3(256), 0, stream,
                     W1, W2, Wv, Woff, Wat, Wo, W1f, W2f, Wvf, Wqf, Wof);
  hipLaunchKernelGGL(k_value_mfma, dim3((int)(NTOK / 32)), dim3(256), 0, stream,
                     src, Wvf, bv, valbf);
  hipLaunchKernelGGL(k_qproj_mfma, dim3((int)(NTOK / 32)), dim3(256), 0, stream,
                     src, pos, Wqf, boff, bat, offbf, attn);
  hipLaunchKernelGGL(k_sample3, dim3((int)(NTOK / 4)), dim3(256), 0, stream,
                     valbf, offbf, attn, refp, src2bf);
  hipLaunchKernelGGL(k_outproj_mfma, dim3((int)(NTOK / 32)), dim3(256), 0, stream,
                     src2bf, Wof, bo, src, g1, b1g, xbf);
  hipLaunchKernelGGL(k_ffn1c, dim3((int)(NTOK / 64), 2), dim3(256), 0, stream,
                     xbf, W1f, b1f, hbf);
  hipLaunchKernelGGL(k_ffn2, dim3((int)(NTOK / 32)), dim3(256), 0, stream,
                     hbf, W2f, b2f, xbf, g2, b2g, out);
}